// Round 6
// baseline (720.137 us; speedup 1.0000x reference)
//
#include <hip/hip_runtime.h>
#include <hip/hip_bf16.h>

#define B_ 2
#define C_ 256
#define N_ 110592
#define CN_ ((size_t)C_ * N_)
#define NCK_ 216          // K-chunks in gram (divides 1728 tiles)
#define T_ 8              // 64-col tiles per chunk: 216*8*64 = 110592

typedef __attribute__((ext_vector_type(4))) float f32x4;
typedef __attribute__((ext_vector_type(8))) short bf16x8;
typedef __attribute__((ext_vector_type(4))) short bf16x4;

__device__ __forceinline__ short f2bf(float f) {
    union { float f; unsigned u; } v; v.f = f;
    unsigned r = (v.u + 0x7fffu + ((v.u >> 16) & 1u)) >> 16;
    return (short)(r & 0xffffu);
}

__device__ __forceinline__ void gload16(const short* g, short* l) {
    __builtin_amdgcn_global_load_lds(
        (const __attribute__((address_space(1))) void*)g,
        (__attribute__((address_space(3))) void*)l, 16, 0, 0);
}

// ---------------- Pass 1: raw Gram (split-K) + rowsums + xf emit ----------
// 1024 thr / 16 waves, wave-tile 64x64 (acc=64 VGPR). 2-phase reg-staged
// pipeline. Also emits x -> bf16 fragment-layout xf from the staged tile.
// NCK=216 -> 432 blocks -> ~2 blocks/CU so barriers overlap across blocks.
__global__ __launch_bounds__(1024, 8) void k_gram(
        const float* __restrict__ x, float* __restrict__ part,
        float* __restrict__ rspart, short* __restrict__ xf, int wxf) {
    __shared__ short Xs[2 * 256 * 72];   // 2 buffers, 256 rows x 144B pitch
    __shared__ float rs_s[256];
    const int t = threadIdx.x, lane = t & 63, wave = t >> 6;
    const int chunk = blockIdx.x, b = blockIdx.y;
    const int k0 = chunk * (T_ * 64);
    const int f4 = t & 15;
    const int crow = t >> 4;
    const int cw0 = (wave & 3) * 64, dw0 = (wave >> 2) * 64;
    const int r16 = lane & 15, g16 = lane >> 4;
    const float* xb = x + (size_t)b * CN_;
    short* xfb = xf + (size_t)b * CN_;

    f32x4 acc[4][4];
#pragma unroll
    for (int i = 0; i < 4; ++i)
#pragma unroll
        for (int j = 0; j < 4; ++j) acc[i][j] = f32x4{0.f, 0.f, 0.f, 0.f};
    float rs[4] = {0.f, 0.f, 0.f, 0.f};

    f32x4 va[4];
#pragma unroll
    for (int q = 0; q < 4; ++q)
        va[q] = *(const f32x4*)(xb + (size_t)(q * 64 + crow) * N_ + k0 + f4 * 4);

    for (int tt = 0; tt < T_; ++tt) {
        const int buf = (tt & 1) * 18432;
#pragma unroll
        for (int q = 0; q < 4; ++q) {
            f32x4 v = va[q];
            rs[q] += (v.x + v.y) + (v.z + v.w);
            bf16x4 h;
            h.x = f2bf(v.x); h.y = f2bf(v.y); h.z = f2bf(v.z); h.w = f2bf(v.w);
            *(bf16x4*)(Xs + buf + (q * 64 + crow) * 72 + f4 * 4) = h;
        }
        __syncthreads();
        if (tt + 1 < T_) {
#pragma unroll
            for (int q = 0; q < 4; ++q)
                va[q] = *(const f32x4*)(xb + (size_t)(q * 64 + crow) * N_ +
                                        k0 + (tt + 1) * 64 + f4 * 4);
        }
        // emit xf (bf16 fragment layout) from the staged LDS tile
        if (wxf) {
            const int kglob0 = k0 + tt * 64;
#pragma unroll
            for (int i2 = 0; i2 < 2; ++i2) {
                int s = i2 * 1024 + t;
                int kg = s >> 6, nn = s & 63;
                bf16x8 h;
#pragma unroll
                for (int j = 0; j < 8; ++j)
                    h[j] = Xs[buf + (kg * 8 + j) * 72 + nn];
                *(bf16x8*)(xfb + ((size_t)kg * N_ + kglob0 + nn) * 8) = h;
            }
        }
#pragma unroll
        for (int k2 = 0; k2 < 2; ++k2) {
            bf16x8 afr[4];
#pragma unroll
            for (int ct = 0; ct < 4; ++ct)
                afr[ct] = *(const bf16x8*)(Xs + buf + (cw0 + ct * 16 + r16) * 72 +
                                           (k2 * 4 + g16) * 8);
#pragma unroll
            for (int dt = 0; dt < 4; ++dt) {
                bf16x8 bfr = *(const bf16x8*)(Xs + buf + (dw0 + dt * 16 + r16) * 72 +
                                              (k2 * 4 + g16) * 8);
#pragma unroll
                for (int ct = 0; ct < 4; ++ct)
                    acc[ct][dt] = __builtin_amdgcn_mfma_f32_16x16x32_bf16(
                        afr[ct], bfr, acc[ct][dt], 0, 0, 0);
            }
        }
    }

#pragma unroll
    for (int q = 0; q < 4; ++q) {
        float r = rs[q];
        r += __shfl_xor(r, 1);
        r += __shfl_xor(r, 2);
        r += __shfl_xor(r, 4);
        r += __shfl_xor(r, 8);
        if ((t & 15) == 0) rs_s[q * 64 + crow] = r;
    }
    __syncthreads();
    if (t < 256) rspart[((size_t)b * NCK_ + chunk) * C_ + t] = rs_s[t];

    float* pp = part + ((size_t)b * NCK_ + chunk) * (C_ * C_);
#pragma unroll
    for (int ct = 0; ct < 4; ++ct)
#pragma unroll
        for (int dt = 0; dt < 4; ++dt) {
            int d = dw0 + dt * 16 + r16;
#pragma unroll
            for (int rr = 0; rr < 4; ++rr) {
                int c = cw0 + ct * 16 + g16 * 4 + rr;
                pp[(size_t)c * C_ + d] = acc[ct][dt][rr];
            }
        }
}

// ------------- reduce partial Grams + fused stats (mean, rsig) -----------
__global__ void k_reduce(const float* __restrict__ part, const float* __restrict__ rspart,
                         float* __restrict__ Graw, float* __restrict__ mean,
                         float* __restrict__ rsig) {
    __shared__ float diag_s;
    __shared__ float red[256];
    int bid = blockIdx.x;
    int b = bid >> 8, c = bid & 255;
    int d = threadIdx.x;
    float s = 0.f;
    for (int p = 0; p < NCK_; ++p)
        s += part[(((size_t)b * NCK_ + p) * (C_ * C_)) + (size_t)c * C_ + d];
    Graw[((size_t)b * C_ + c) * C_ + d] = s;
    if (d == c) diag_s = s;
    float rsum = 0.f;
    for (int p = d; p < NCK_; p += 256)
        rsum += rspart[((size_t)b * NCK_ + p) * C_ + c];
    red[d] = rsum;
    __syncthreads();
    if (d < 128) red[d] += red[d + 128];
    __syncthreads();
    if (d < 64) red[d] += red[d + 64];
    __syncthreads();
    if (d == 0) {
        float tot = 0.f;
#pragma unroll
        for (int i = 0; i < 64; ++i) tot += red[i];
        float m = tot / (float)N_;
        float var = diag_s / (float)N_ - m * m;
        mean[b * C_ + c] = m;
        rsig[b * C_ + c] = rsqrtf(var + 1e-5f);
    }
}

// ---------------- P = Wq * Gn ----------------
__global__ void k_gemm1(const float* __restrict__ Wq, const float* __restrict__ Graw,
                        const float* __restrict__ mean, const float* __restrict__ rsig,
                        float* __restrict__ P) {
    int bid = blockIdx.x; int b = bid >> 8, c = bid & 255; int d = threadIdx.x;
    const float* G = Graw + (size_t)b * C_ * C_;
    const float* mb = mean + b * C_;
    const float* rb = rsig + b * C_;
    float md = mb[d], rd = rb[d];
    float a1 = 0.f, a2 = 0.f;
    for (int e = 0; e < C_; ++e) {
        float w = Wq[(size_t)c * C_ + e] * rb[e];
        a1 += w * G[(size_t)e * C_ + d];
        a2 += w * mb[e];
    }
    P[((size_t)b * C_ + c) * C_ + d] = rd * a1 - (float)N_ * md * rd * a2;
}

// ---------------- atten = softmax(P*Wk^T + N bq bk^T)/16 + outer/16 ------
__global__ void k_attn(const float* __restrict__ P, const float* __restrict__ Wk,
                       const float* __restrict__ bq, const float* __restrict__ bk,
                       const float* __restrict__ outer, float* __restrict__ atten) {
    __shared__ float Pr_s[256];
    __shared__ float red[8];
    int bid = blockIdx.x; int b = bid >> 8, c = bid & 255; int d = threadIdx.x;
    int lane = d & 63, w = d >> 6;
    Pr_s[d] = P[((size_t)b * C_ + c) * C_ + d];
    __syncthreads();
    float a = 0.f;
#pragma unroll 4
    for (int e4 = 0; e4 < 64; ++e4) {
        f32x4 wv = *(const f32x4*)(Wk + (size_t)d * C_ + e4 * 4);
        f32x4 pv = *(const f32x4*)(Pr_s + e4 * 4);
        a += wv.x * pv.x + wv.y * pv.y + wv.z * pv.z + wv.w * pv.w;
    }
    float v = a + (float)N_ * bq[c] * bk[d];
    float m = v;
    for (int off = 32; off; off >>= 1) m = fmaxf(m, __shfl_xor(m, off));
    if (lane == 0) red[w] = m;
    __syncthreads();
    m = fmaxf(fmaxf(red[0], red[1]), fmaxf(red[2], red[3]));
    float e = __expf(v - m);
    float s = e;
    for (int off = 32; off; off >>= 1) s += __shfl_xor(s, off);
    if (lane == 0) red[4 + w] = s;
    __syncthreads();
    s = red[4] + red[5] + red[6] + red[7];
    atten[((size_t)b * C_ + c) * C_ + d] = e / (s * 16.f) + outer[(size_t)c * C_ + d] * 0.0625f;
}

// ------------- A = (atten*Wv + I)*diag(rsig) in FRAGMENT layout, beta ----
__global__ void k_gemm3(const float* __restrict__ atten, const float* __restrict__ Wv,
                        const float* __restrict__ bv, const float* __restrict__ mean,
                        const float* __restrict__ rsig, short* __restrict__ Abf,
                        float* __restrict__ beta) {
    __shared__ float red[4];
    int bid = blockIdx.x; int b = bid >> 8, c = bid & 255; int g = threadIdx.x;
    int lane = g & 63, w = g >> 6;
    const float* at = atten + ((size_t)b * C_ + c) * C_;
    float a = 0.f;
    for (int d = 0; d < C_; ++d)
        a += at[d] * Wv[(size_t)d * C_ + g];
    float Ag = (a + ((g == c) ? 1.f : 0.f)) * rsig[b * C_ + g];
    Abf[(size_t)b * C_ * C_ + ((size_t)(g >> 3) * C_ + c) * 8 + (g & 7)] = f2bf(Ag);
    float u = at[g] * bv[g] - Ag * mean[b * C_ + g];
    for (int off = 32; off; off >>= 1) u += __shfl_xor(u, off);
    if (lane == 0) red[w] = u;
    __syncthreads();
    if (g == 0) beta[b * C_ + c] = red[0] + red[1] + red[2] + red[3];
}

// ------------- Pass 2: out = A*x + beta ------------------------------------
__global__ __launch_bounds__(512, 4) void k_out2(
        const short* __restrict__ xf, const short* __restrict__ Abf,
        const float* __restrict__ beta, float* __restrict__ out) {
    __shared__ short Xt[2 * 8192];      // 2 x 16 KB
    __shared__ float Wb[8 * 32 * 33];   // wave-private store-transpose
    const int t = threadIdx.x, lane = t & 63, wave = t >> 6;
    const int nb = blockIdx.x, b = blockIdx.y;
    const int col = lane & 15, g16 = lane >> 4;
    const int cw0 = wave * 32;
    const int r8 = lane >> 3, s8 = lane & 7;
    const int n_blk = nb * 256;
    const short* Ab = Abf + (size_t)b * C_ * C_;
    const short* xfb = xf + (size_t)b * CN_;
    float* ob = out + (size_t)b * CN_;
    float* wl = Wb + wave * (32 * 33);

    // A-slice preload: 16 frags = 64 VGPR
    bf16x8 Af[2][8];
#pragma unroll
    for (int ct = 0; ct < 2; ++ct)
#pragma unroll
        for (int ks = 0; ks < 8; ++ks)
            Af[ct][ks] = *(const bf16x8*)(Ab +
                ((size_t)((ks * 4 + g16) * 256 + cw0 + ct * 16 + col)) * 8);
    float bet[4];
#pragma unroll
    for (int j = 0; j < 4; ++j) bet[j] = beta[b * C_ + cw0 + j * 8 + r8];

#define STAGE(BUF, N0)                                                        \
    {                                                                         \
        _Pragma("unroll")                                                     \
        for (int r = 0; r < 2; ++r) {                                         \
            int s = r * 512 + t;                                              \
            int kg = s >> 5, nsl = s & 31;                                    \
            int nn = nsl ^ (kg & 3);                                          \
            gload16(xfb + ((size_t)kg * N_ + (N0) + nn) * 8,                  \
                    Xt + (BUF) * 8192 + s * 8);                               \
        }                                                                     \
    }

    STAGE(0, n_blk)
    __syncthreads();

    for (int it = 0; it < 8; ++it) {
        const int cur = it & 1;
        if (it + 1 < 8) STAGE(cur ^ 1, n_blk + (it + 1) * 32)
        const int n0 = n_blk + it * 32;

        f32x4 acc[2][2];
#pragma unroll
        for (int i = 0; i < 2; ++i) {
            acc[i][0] = f32x4{0.f, 0.f, 0.f, 0.f};
            acc[i][1] = f32x4{0.f, 0.f, 0.f, 0.f};
        }
#pragma unroll
        for (int ks = 0; ks < 8; ++ks) {
            const int kg = ks * 4 + g16;
            bf16x8 x0 = *(const bf16x8*)(Xt + cur * 8192 +
                                         (kg * 32 + (col ^ (kg & 3))) * 8);
            bf16x8 x1 = *(const bf16x8*)(Xt + cur * 8192 +
                                         (kg * 32 + ((16 + col) ^ (kg & 3))) * 8);
            acc[0][0] = __builtin_amdgcn_mfma_f32_16x16x32_bf16(Af[0][ks], x0, acc[0][0], 0, 0, 0);
            acc[1][0] = __builtin_amdgcn_mfma_f32_16x16x32_bf16(Af[1][ks], x0, acc[1][0], 0, 0, 0);
            acc[0][1] = __builtin_amdgcn_mfma_f32_16x16x32_bf16(Af[0][ks], x1, acc[0][1], 0, 0, 0);
            acc[1][1] = __builtin_amdgcn_mfma_f32_16x16x32_bf16(Af[1][ks], x1, acc[1][1], 0, 0, 0);
        }
        // wave-private transpose (pitch 33 -> ~2-way banks)
#pragma unroll
        for (int ct = 0; ct < 2; ++ct)
#pragma unroll
            for (int nt = 0; nt < 2; ++nt)
#pragma unroll
                for (int rr = 0; rr < 4; ++rr)
                    wl[(ct * 16 + g16 * 4 + rr) * 33 + nt * 16 + col] = acc[ct][nt][rr];
#pragma unroll
        for (int j = 0; j < 4; ++j) {
            f32x4 v = *(const f32x4*)(wl + (j * 8 + r8) * 33 + s8 * 4);
            float bb = bet[j];
            v.x += bb; v.y += bb; v.z += bb; v.w += bb;
            *(f32x4*)(ob + (size_t)(cw0 + j * 8 + r8) * N_ + n0 + s8 * 4) = v;
        }
        __syncthreads();
    }
#undef STAGE
}

// ------------- Pass 2 (fallback, small ws): gathers f32 x ----------------
__global__ __launch_bounds__(512) void k_out_f32(
        const float* __restrict__ x, const short* __restrict__ Abf,
        const float* __restrict__ beta, float* __restrict__ out) {
    __shared__ float beta_s[256];
    const int t = threadIdx.x, lane = t & 63, wave = t >> 6;
    const int nb = blockIdx.x, b = blockIdx.y;
    const int col = lane & 15, g16 = lane >> 4;
    const int n_w = nb * 256 + wave * 32;
    if (t < 256) beta_s[t] = beta[b * C_ + t];
    __syncthreads();
    const short* Ab = Abf + (size_t)b * C_ * C_;
    const float* xb = x + (size_t)b * CN_;
    float* ob = out + (size_t)b * CN_;

    f32x4 acc[16][2];
#pragma unroll
    for (int i = 0; i < 16; ++i) {
        acc[i][0] = f32x4{0.f, 0.f, 0.f, 0.f};
        acc[i][1] = f32x4{0.f, 0.f, 0.f, 0.f};
    }
    float pf[2][16];
#define XL(KS, NT, J) xb[(size_t)((KS)*32 + g16 * 8 + (J)) * N_ + n_w + (NT)*16 + col]
#pragma unroll
    for (int j = 0; j < 8; ++j) { pf[0][j] = XL(0, 0, j); pf[0][8 + j] = XL(0, 1, j); }
#pragma unroll
    for (int ks = 0; ks < 8; ++ks) {
        if (ks + 1 < 8) {
#pragma unroll
            for (int j = 0; j < 8; ++j) {
                pf[(ks + 1) & 1][j] = XL(ks + 1, 0, j);
                pf[(ks + 1) & 1][8 + j] = XL(ks + 1, 1, j);
            }
        }
        bf16x8 xa, xv;
#pragma unroll
        for (int j = 0; j < 8; ++j) {
            xa[j] = f2bf(pf[ks & 1][j]);
            xv[j] = f2bf(pf[ks & 1][8 + j]);
        }
#pragma unroll
        for (int ct = 0; ct < 16; ++ct) {
            bf16x8 afr = *(const bf16x8*)(Ab + ((size_t)((ks * 4 + g16) * 256 + ct * 16 + col)) * 8);
            acc[ct][0] = __builtin_amdgcn_mfma_f32_16x16x32_bf16(afr, xa, acc[ct][0], 0, 0, 0);
            acc[ct][1] = __builtin_amdgcn_mfma_f32_16x16x32_bf16(afr, xv, acc[ct][1], 0, 0, 0);
        }
    }
#undef XL
#pragma unroll
    for (int ct = 0; ct < 16; ++ct)
#pragma unroll
        for (int nt = 0; nt < 2; ++nt) {
            int n = n_w + nt * 16 + col;
#pragma unroll
            for (int rr = 0; rr < 4; ++rr) {
                int c = ct * 16 + g16 * 4 + rr;
                ob[(size_t)c * N_ + n] = acc[ct][nt][rr] + beta_s[c];
            }
        }
}

extern "C" void kernel_launch(void* const* d_in, const int* in_sizes, int n_in,
                              void* d_out, int out_size, void* d_ws, size_t ws_size,
                              hipStream_t stream) {
    (void)in_sizes; (void)n_in; (void)out_size;
    const float* x     = (const float*)d_in[0];
    const float* Wq    = (const float*)d_in[1];
    const float* bq    = (const float*)d_in[2];
    const float* Wk    = (const float*)d_in[3];
    const float* bk    = (const float*)d_in[4];
    const float* Wv    = (const float*)d_in[5];
    const float* bv    = (const float*)d_in[6];
    const float* outer = (const float*)d_in[7];
    float* out = (float*)d_out;

    char* w = (char*)d_ws;
    float* mean   = (float*)(w + 0);
    float* rsig   = (float*)(w + 2048);
    float* beta   = (float*)(w + 4096);
    float* rspart = (float*)(w + 8192);                 // 216*2*256*4 = 442368
    float* Graw   = (float*)(w + 458752);               // 512K
    float* P      = (float*)(w + 983040);               // 512K
    float* atten  = (float*)(w + 1507328);              // 512K
    short* Abf    = (short*)(w + 2031616);              // 256K
    const size_t fixed = 2359296;                       // 2.25 MB
    const size_t part_bytes = (size_t)NCK_ * B_ * C_ * C_ * 4;   // 113.25 MB
    const size_t xf_bytes = (size_t)B_ * CN_ * 2;                // 113.25 MB
    float* part = (float*)(w + fixed);
    short* xf   = (short*)(w + fixed + part_bytes);

    const bool big = ws_size >= fixed + part_bytes + xf_bytes;

    k_gram  <<<dim3(NCK_, B_), 1024, 0, stream>>>(x, part, rspart, xf, big ? 1 : 0);
    k_reduce<<<dim3(B_ * C_), 256, 0, stream>>>(part, rspart, Graw, mean, rsig);
    k_gemm1 <<<dim3(B_ * C_), C_, 0, stream>>>(Wq, Graw, mean, rsig, P);
    k_attn  <<<dim3(B_ * C_), C_, 0, stream>>>(P, Wk, bq, bk, outer, atten);
    k_gemm3 <<<dim3(B_ * C_), C_, 0, stream>>>(atten, Wv, bv, mean, rsig, Abf, beta);
    if (big) {
        k_out2  <<<dim3(N_ / 256, B_), 512, 0, stream>>>(xf, Abf, beta, out);
    } else {
        k_out_f32<<<dim3(N_ / 256, B_), 512, 0, stream>>>(x, Abf, beta, out);
    }
}

// Round 7
// 369.269 us; speedup vs baseline: 1.9502x; 1.9502x over previous
//
#include <hip/hip_runtime.h>
#include <hip/hip_bf16.h>

#define B_ 2
#define C_ 256
#define N_ 110592
#define CN_ ((size_t)C_ * N_)
#define NCK_ 108          // K-chunks in gram
#define TT_ 8             // 128-col tiles per chunk: 108*8*128 = 110592
#define GP_ 136           // gram LDS pitch in shorts (272 B == 4 banks mod 32)

typedef __attribute__((ext_vector_type(4))) float f32x4;
typedef __attribute__((ext_vector_type(8))) short bf16x8;
typedef __attribute__((ext_vector_type(4))) short bf16x4;

__device__ __forceinline__ short f2bf(float f) {
    union { float f; unsigned u; } v; v.f = f;
    unsigned r = (v.u + 0x7fffu + ((v.u >> 16) & 1u)) >> 16;
    return (short)(r & 0xffffu);
}

__device__ __forceinline__ void gload16(const short* g, short* l) {
    __builtin_amdgcn_global_load_lds(
        (const __attribute__((address_space(1))) void*)g,
        (__attribute__((address_space(3))) void*)l, 16, 0, 0);
}

// ---------------- Pass 1: raw Gram (split-K) + rowsums + xf emit ----------
// 1024 thr / 16 waves, wave-tile 64x64 (acc=64). Tile = 256ch x 128n so
// x reads are 512-B contiguous segments (2 per wave instr). Dbuf LDS,
// 1 barrier/tile, reg-staged prefetch (va=32 VGPR).
__global__ __launch_bounds__(1024, 4) void k_gram(
        const float* __restrict__ x, float* __restrict__ part,
        float* __restrict__ rspart, short* __restrict__ xf, int wxf) {
    __shared__ short Xs[2 * 256 * GP_];   // 2 x 68 KB
    __shared__ float rs_s[256];
    const int t = threadIdx.x, lane = t & 63, wave = t >> 6;
    const int chunk = blockIdx.x, b = blockIdx.y;
    const int k0 = chunk * (TT_ * 128);
    const int colg = t & 31;              // 16B col-group (n-local = colg*4)
    const int rowp = t >> 5;              // 0..31 ; row = p*32 + rowp
    const int cw0 = (wave & 3) * 64, dw0 = (wave >> 2) * 64;
    const int r16 = lane & 15, g16 = lane >> 4;
    const float* xb = x + (size_t)b * CN_;
    short* xfb = xf + (size_t)b * CN_;

    f32x4 acc[4][4];
#pragma unroll
    for (int i = 0; i < 4; ++i)
#pragma unroll
        for (int j = 0; j < 4; ++j) acc[i][j] = f32x4{0.f, 0.f, 0.f, 0.f};
    float rs[8] = {0.f, 0.f, 0.f, 0.f, 0.f, 0.f, 0.f, 0.f};

    f32x4 va[8];
#pragma unroll
    for (int p = 0; p < 8; ++p)
        va[p] = *(const f32x4*)(xb + (size_t)(p * 32 + rowp) * N_ + k0 + colg * 4);

    for (int tt = 0; tt < TT_; ++tt) {
        const int buf = (tt & 1) * (256 * GP_);
        // convert + LDS write + rowsum accumulate
#pragma unroll
        for (int p = 0; p < 8; ++p) {
            f32x4 v = va[p];
            rs[p] += (v.x + v.y) + (v.z + v.w);
            bf16x4 h;
            h.x = f2bf(v.x); h.y = f2bf(v.y); h.z = f2bf(v.z); h.w = f2bf(v.w);
            *(bf16x4*)(Xs + buf + (p * 32 + rowp) * GP_ + colg * 4) = h;
        }
        __syncthreads();
        if (tt + 1 < TT_) {
#pragma unroll
            for (int p = 0; p < 8; ++p)
                va[p] = *(const f32x4*)(xb + (size_t)(p * 32 + rowp) * N_ +
                                        k0 + (tt + 1) * 128 + colg * 4);
        }
        // emit xf (ch-packed bf16 fragment layout) from the staged tile
        if (wxf) {
            const int ng0 = k0 + tt * 128;
#pragma unroll
            for (int it = 0; it < 4; ++it) {
                int s = it * 1024 + t;
                int kg = s >> 7, nn = s & 127;
                bf16x8 h;
#pragma unroll
                for (int j = 0; j < 8; ++j)
                    h[j] = Xs[buf + (kg * 8 + j) * GP_ + nn];
                *(bf16x8*)(xfb + ((size_t)kg * N_ + ng0 + nn) * 8) = h;
            }
        }
        // MFMA over K=128 (4 k-steps of 32)
#pragma unroll
        for (int kst = 0; kst < 4; ++kst) {
            bf16x8 afr[4];
#pragma unroll
            for (int ct = 0; ct < 4; ++ct)
                afr[ct] = *(const bf16x8*)(Xs + buf + (cw0 + ct * 16 + r16) * GP_ +
                                           kst * 32 + g16 * 8);
#pragma unroll
            for (int dt = 0; dt < 4; ++dt) {
                bf16x8 bfr = *(const bf16x8*)(Xs + buf + (dw0 + dt * 16 + r16) * GP_ +
                                              kst * 32 + g16 * 8);
#pragma unroll
                for (int ct = 0; ct < 4; ++ct)
                    acc[ct][dt] = __builtin_amdgcn_mfma_f32_16x16x32_bf16(
                        afr[ct], bfr, acc[ct][dt], 0, 0, 0);
            }
        }
    }

    // rowsums: 32 threads (t>>5 fixed) share each row; reduce within 32-lane half
#pragma unroll
    for (int p = 0; p < 8; ++p) {
        float r = rs[p];
        r += __shfl_xor(r, 1);
        r += __shfl_xor(r, 2);
        r += __shfl_xor(r, 4);
        r += __shfl_xor(r, 8);
        r += __shfl_xor(r, 16);
        if ((t & 31) == 0) rs_s[p * 32 + rowp] = r;
    }
    __syncthreads();
    if (t < 256) rspart[((size_t)b * NCK_ + chunk) * C_ + t] = rs_s[t];

    float* pp = part + ((size_t)b * NCK_ + chunk) * (C_ * C_);
#pragma unroll
    for (int ct = 0; ct < 4; ++ct)
#pragma unroll
        for (int dt = 0; dt < 4; ++dt) {
            int d = dw0 + dt * 16 + r16;
#pragma unroll
            for (int rr = 0; rr < 4; ++rr) {
                int c = cw0 + ct * 16 + g16 * 4 + rr;
                pp[(size_t)c * C_ + d] = acc[ct][dt][rr];
            }
        }
}

// ------------- reduce partial Grams + fused stats (mean, rsig) -----------
__global__ void k_reduce(const float* __restrict__ part, const float* __restrict__ rspart,
                         float* __restrict__ Graw, float* __restrict__ mean,
                         float* __restrict__ rsig) {
    __shared__ float diag_s;
    __shared__ float red[256];
    int bid = blockIdx.x;
    int b = bid >> 8, c = bid & 255;
    int d = threadIdx.x;
    float s = 0.f;
    for (int p = 0; p < NCK_; ++p)
        s += part[(((size_t)b * NCK_ + p) * (C_ * C_)) + (size_t)c * C_ + d];
    Graw[((size_t)b * C_ + c) * C_ + d] = s;
    if (d == c) diag_s = s;
    float rsum = 0.f;
    for (int p = d; p < NCK_; p += 256)
        rsum += rspart[((size_t)b * NCK_ + p) * C_ + c];
    red[d] = rsum;
    __syncthreads();
    if (d < 128) red[d] += red[d + 128];
    __syncthreads();
    if (d < 64) red[d] += red[d + 64];
    __syncthreads();
    if (d == 0) {
        float tot = 0.f;
#pragma unroll
        for (int i = 0; i < 64; ++i) tot += red[i];
        float m = tot / (float)N_;
        float var = diag_s / (float)N_ - m * m;
        mean[b * C_ + c] = m;
        rsig[b * C_ + c] = rsqrtf(var + 1e-5f);
    }
}

// ---------------- P = Wq * Gn ----------------
__global__ void k_gemm1(const float* __restrict__ Wq, const float* __restrict__ Graw,
                        const float* __restrict__ mean, const float* __restrict__ rsig,
                        float* __restrict__ P) {
    int bid = blockIdx.x; int b = bid >> 8, c = bid & 255; int d = threadIdx.x;
    const float* G = Graw + (size_t)b * C_ * C_;
    const float* mb = mean + b * C_;
    const float* rb = rsig + b * C_;
    float md = mb[d], rd = rb[d];
    float a1 = 0.f, a2 = 0.f;
    for (int e = 0; e < C_; ++e) {
        float w = Wq[(size_t)c * C_ + e] * rb[e];
        a1 += w * G[(size_t)e * C_ + d];
        a2 += w * mb[e];
    }
    P[((size_t)b * C_ + c) * C_ + d] = rd * a1 - (float)N_ * md * rd * a2;
}

// ---------------- atten = softmax(P*Wk^T + N bq bk^T)/16 + outer/16 ------
__global__ void k_attn(const float* __restrict__ P, const float* __restrict__ Wk,
                       const float* __restrict__ bq, const float* __restrict__ bk,
                       const float* __restrict__ outer, float* __restrict__ atten) {
    __shared__ float Pr_s[256];
    __shared__ float red[8];
    int bid = blockIdx.x; int b = bid >> 8, c = bid & 255; int d = threadIdx.x;
    int lane = d & 63, w = d >> 6;
    Pr_s[d] = P[((size_t)b * C_ + c) * C_ + d];
    __syncthreads();
    float a = 0.f;
#pragma unroll 4
    for (int e4 = 0; e4 < 64; ++e4) {
        f32x4 wv = *(const f32x4*)(Wk + (size_t)d * C_ + e4 * 4);
        f32x4 pv = *(const f32x4*)(Pr_s + e4 * 4);
        a += wv.x * pv.x + wv.y * pv.y + wv.z * pv.z + wv.w * pv.w;
    }
    float v = a + (float)N_ * bq[c] * bk[d];
    float m = v;
    for (int off = 32; off; off >>= 1) m = fmaxf(m, __shfl_xor(m, off));
    if (lane == 0) red[w] = m;
    __syncthreads();
    m = fmaxf(fmaxf(red[0], red[1]), fmaxf(red[2], red[3]));
    float e = __expf(v - m);
    float s = e;
    for (int off = 32; off; off >>= 1) s += __shfl_xor(s, off);
    if (lane == 0) red[4 + w] = s;
    __syncthreads();
    s = red[4] + red[5] + red[6] + red[7];
    atten[((size_t)b * C_ + c) * C_ + d] = e / (s * 16.f) + outer[(size_t)c * C_ + d] * 0.0625f;
}

// ------------- A = (atten*Wv + I)*diag(rsig) in FRAGMENT layout, beta ----
__global__ void k_gemm3(const float* __restrict__ atten, const float* __restrict__ Wv,
                        const float* __restrict__ bv, const float* __restrict__ mean,
                        const float* __restrict__ rsig, short* __restrict__ Abf,
                        float* __restrict__ beta) {
    __shared__ float red[4];
    int bid = blockIdx.x; int b = bid >> 8, c = bid & 255; int g = threadIdx.x;
    int lane = g & 63, w = g >> 6;
    const float* at = atten + ((size_t)b * C_ + c) * C_;
    float a = 0.f;
    for (int d = 0; d < C_; ++d)
        a += at[d] * Wv[(size_t)d * C_ + g];
    float Ag = (a + ((g == c) ? 1.f : 0.f)) * rsig[b * C_ + g];
    Abf[(size_t)b * C_ * C_ + ((size_t)(g >> 3) * C_ + c) * 8 + (g & 7)] = f2bf(Ag);
    float u = at[g] * bv[g] - Ag * mean[b * C_ + g];
    for (int off = 32; off; off >>= 1) u += __shfl_xor(u, off);
    if (lane == 0) red[w] = u;
    __syncthreads();
    if (g == 0) beta[b * C_ + c] = red[0] + red[1] + red[2] + red[3];
}

// ------------- Pass 2: out = A*x + beta ------------------------------------
__global__ __launch_bounds__(512, 4) void k_out2(
        const short* __restrict__ xf, const short* __restrict__ Abf,
        const float* __restrict__ beta, float* __restrict__ out) {
    __shared__ short Xt[2 * 8192];      // 2 x 16 KB
    __shared__ float Wb[8 * 32 * 33];   // wave-private store-transpose
    const int t = threadIdx.x, lane = t & 63, wave = t >> 6;
    const int nb = blockIdx.x, b = blockIdx.y;
    const int col = lane & 15, g16 = lane >> 4;
    const int cw0 = wave * 32;
    const int r8 = lane >> 3, s8 = lane & 7;
    const int n_blk = nb * 256;
    const short* Ab = Abf + (size_t)b * C_ * C_;
    const short* xfb = xf + (size_t)b * CN_;
    float* ob = out + (size_t)b * CN_;
    float* wl = Wb + wave * (32 * 33);

    // A-slice preload: 16 frags = 64 VGPR
    bf16x8 Af[2][8];
#pragma unroll
    for (int ct = 0; ct < 2; ++ct)
#pragma unroll
        for (int ks = 0; ks < 8; ++ks)
            Af[ct][ks] = *(const bf16x8*)(Ab +
                ((size_t)((ks * 4 + g16) * 256 + cw0 + ct * 16 + col)) * 8);
    float bet[4];
#pragma unroll
    for (int j = 0; j < 4; ++j) bet[j] = beta[b * C_ + cw0 + j * 8 + r8];

#define STAGE(BUF, N0)                                                        \
    {                                                                         \
        _Pragma("unroll")                                                     \
        for (int r = 0; r < 2; ++r) {                                         \
            int s = r * 512 + t;                                              \
            int kg = s >> 5, nsl = s & 31;                                    \
            int nn = nsl ^ (kg & 3);                                          \
            gload16(xfb + ((size_t)kg * N_ + (N0) + nn) * 8,                  \
                    Xt + (BUF) * 8192 + s * 8);                               \
        }                                                                     \
    }

    STAGE(0, n_blk)
    __syncthreads();

    for (int it = 0; it < 8; ++it) {
        const int cur = it & 1;
        if (it + 1 < 8) STAGE(cur ^ 1, n_blk + (it + 1) * 32)
        const int n0 = n_blk + it * 32;

        f32x4 acc[2][2];
#pragma unroll
        for (int i = 0; i < 2; ++i) {
            acc[i][0] = f32x4{0.f, 0.f, 0.f, 0.f};
            acc[i][1] = f32x4{0.f, 0.f, 0.f, 0.f};
        }
#pragma unroll
        for (int ks = 0; ks < 8; ++ks) {
            const int kg = ks * 4 + g16;
            bf16x8 x0 = *(const bf16x8*)(Xt + cur * 8192 +
                                         (kg * 32 + (col ^ (kg & 3))) * 8);
            bf16x8 x1 = *(const bf16x8*)(Xt + cur * 8192 +
                                         (kg * 32 + ((16 + col) ^ (kg & 3))) * 8);
            acc[0][0] = __builtin_amdgcn_mfma_f32_16x16x32_bf16(Af[0][ks], x0, acc[0][0], 0, 0, 0);
            acc[1][0] = __builtin_amdgcn_mfma_f32_16x16x32_bf16(Af[1][ks], x0, acc[1][0], 0, 0, 0);
            acc[0][1] = __builtin_amdgcn_mfma_f32_16x16x32_bf16(Af[0][ks], x1, acc[0][1], 0, 0, 0);
            acc[1][1] = __builtin_amdgcn_mfma_f32_16x16x32_bf16(Af[1][ks], x1, acc[1][1], 0, 0, 0);
        }
        // wave-private transpose (pitch 33 -> ~2-way banks)
#pragma unroll
        for (int ct = 0; ct < 2; ++ct)
#pragma unroll
            for (int nt = 0; nt < 2; ++nt)
#pragma unroll
                for (int rr = 0; rr < 4; ++rr)
                    wl[(ct * 16 + g16 * 4 + rr) * 33 + nt * 16 + col] = acc[ct][nt][rr];
#pragma unroll
        for (int j = 0; j < 4; ++j) {
            f32x4 v = *(const f32x4*)(wl + (j * 8 + r8) * 33 + s8 * 4);
            float bb = bet[j];
            v.x += bb; v.y += bb; v.z += bb; v.w += bb;
            *(f32x4*)(ob + (size_t)(cw0 + j * 8 + r8) * N_ + n0 + s8 * 4) = v;
        }
        __syncthreads();
    }
#undef STAGE
}

// ------------- Pass 2 (fallback, small ws): gathers f32 x ----------------
__global__ __launch_bounds__(512) void k_out_f32(
        const float* __restrict__ x, const short* __restrict__ Abf,
        const float* __restrict__ beta, float* __restrict__ out) {
    __shared__ float beta_s[256];
    const int t = threadIdx.x, lane = t & 63, wave = t >> 6;
    const int nb = blockIdx.x, b = blockIdx.y;
    const int col = lane & 15, g16 = lane >> 4;
    const int n_w = nb * 256 + wave * 32;
    if (t < 256) beta_s[t] = beta[b * C_ + t];
    __syncthreads();
    const short* Ab = Abf + (size_t)b * C_ * C_;
    const float* xb = x + (size_t)b * CN_;
    float* ob = out + (size_t)b * CN_;

    f32x4 acc[16][2];
#pragma unroll
    for (int i = 0; i < 16; ++i) {
        acc[i][0] = f32x4{0.f, 0.f, 0.f, 0.f};
        acc[i][1] = f32x4{0.f, 0.f, 0.f, 0.f};
    }
    float pf[2][16];
#define XL(KS, NT, J) xb[(size_t)((KS)*32 + g16 * 8 + (J)) * N_ + n_w + (NT)*16 + col]
#pragma unroll
    for (int j = 0; j < 8; ++j) { pf[0][j] = XL(0, 0, j); pf[0][8 + j] = XL(0, 1, j); }
#pragma unroll
    for (int ks = 0; ks < 8; ++ks) {
        if (ks + 1 < 8) {
#pragma unroll
            for (int j = 0; j < 8; ++j) {
                pf[(ks + 1) & 1][j] = XL(ks + 1, 0, j);
                pf[(ks + 1) & 1][8 + j] = XL(ks + 1, 1, j);
            }
        }
        bf16x8 xa, xv;
#pragma unroll
        for (int j = 0; j < 8; ++j) {
            xa[j] = f2bf(pf[ks & 1][j]);
            xv[j] = f2bf(pf[ks & 1][8 + j]);
        }
#pragma unroll
        for (int ct = 0; ct < 16; ++ct) {
            bf16x8 afr = *(const bf16x8*)(Ab + ((size_t)((ks * 4 + g16) * 256 + ct * 16 + col)) * 8);
            acc[ct][0] = __builtin_amdgcn_mfma_f32_16x16x32_bf16(afr, xa, acc[ct][0], 0, 0, 0);
            acc[ct][1] = __builtin_amdgcn_mfma_f32_16x16x32_bf16(afr, xv, acc[ct][1], 0, 0, 0);
        }
    }
#undef XL
#pragma unroll
    for (int ct = 0; ct < 16; ++ct)
#pragma unroll
        for (int nt = 0; nt < 2; ++nt) {
            int n = n_w + nt * 16 + col;
#pragma unroll
            for (int rr = 0; rr < 4; ++rr) {
                int c = ct * 16 + g16 * 4 + rr;
                ob[(size_t)c * N_ + n] = acc[ct][nt][rr] + beta_s[c];
            }
        }
}

extern "C" void kernel_launch(void* const* d_in, const int* in_sizes, int n_in,
                              void* d_out, int out_size, void* d_ws, size_t ws_size,
                              hipStream_t stream) {
    (void)in_sizes; (void)n_in; (void)out_size;
    const float* x     = (const float*)d_in[0];
    const float* Wq    = (const float*)d_in[1];
    const float* bq    = (const float*)d_in[2];
    const float* Wk    = (const float*)d_in[3];
    const float* bk    = (const float*)d_in[4];
    const float* Wv    = (const float*)d_in[5];
    const float* bv    = (const float*)d_in[6];
    const float* outer = (const float*)d_in[7];
    float* out = (float*)d_out;

    char* w = (char*)d_ws;
    float* mean   = (float*)(w + 0);
    float* rsig   = (float*)(w + 2048);
    float* beta   = (float*)(w + 4096);
    float* rspart = (float*)(w + 8192);                 // 108*2*256*4 = 221184
    float* Graw   = (float*)(w + 262144);               // 512K
    float* P      = (float*)(w + 786432);               // 512K
    float* atten  = (float*)(w + 1310720);              // 512K
    short* Abf    = (short*)(w + 1835008);              // 256K
    const size_t fixed = 2097152;                       // 2 MB
    const size_t part_bytes = (size_t)NCK_ * B_ * C_ * C_ * 4;   // 56.6 MB
    const size_t xf_bytes = (size_t)B_ * CN_ * 2;                // 113.25 MB
    float* part = (float*)(w + fixed);
    short* xf   = (short*)(w + fixed + part_bytes);

    const bool big = ws_size >= fixed + part_bytes + xf_bytes;

    k_gram  <<<dim3(NCK_, B_), 1024, 0, stream>>>(x, part, rspart, xf, big ? 1 : 0);
    k_reduce<<<dim3(B_ * C_), 256, 0, stream>>>(part, rspart, Graw, mean, rsig);
    k_gemm1 <<<dim3(B_ * C_), C_, 0, stream>>>(Wq, Graw, mean, rsig, P);
    k_attn  <<<dim3(B_ * C_), C_, 0, stream>>>(P, Wk, bq, bk, outer, atten);
    k_gemm3 <<<dim3(B_ * C_), C_, 0, stream>>>(atten, Wv, bv, mean, rsig, Abf, beta);
    if (big) {
        k_out2  <<<dim3(N_ / 256, B_), 512, 0, stream>>>(xf, Abf, beta, out);
    } else {
        k_out_f32<<<dim3(N_ / 256, B_), 512, 0, stream>>>(x, Abf, beta, out);
    }
}

// Round 8
// 285.127 us; speedup vs baseline: 2.5257x; 1.2951x over previous
//
#include <hip/hip_runtime.h>
#include <hip/hip_bf16.h>

#define B_ 2
#define C_ 256
#define N_ 110592
#define CN_ ((size_t)C_ * N_)
#define NCK_ 108          // K-chunks in gram
#define T_ 16             // 64-col tiles per chunk: 108*16*64 = 110592

typedef __attribute__((ext_vector_type(4))) float f32x4;
typedef __attribute__((ext_vector_type(8))) short bf16x8;
typedef __attribute__((ext_vector_type(4))) short bf16x4;

__device__ __forceinline__ short f2bf(float f) {
    union { float f; unsigned u; } v; v.f = f;
    unsigned r = (v.u + 0x7fffu + ((v.u >> 16) & 1u)) >> 16;
    return (short)(r & 0xffffu);
}

__device__ __forceinline__ void gload16(const short* g, short* l) {
    __builtin_amdgcn_global_load_lds(
        (const __attribute__((address_space(1))) void*)g,
        (__attribute__((address_space(3))) void*)l, 16, 0, 0);
}

// ---------------- Pass 1: raw Gram (split-K, split-d) + rowsums + xf ------
// 512 thr / 8 waves, block tile 256(c) x 128(d), wave-tile 64x64.
// grid (NCK, 2, B) = 432 blocks -> 2 blocks/CU: cross-block TLP hides the
// per-tile barrier + load latency. acc=64 AGPR + ~56 VGPR <= 128 budget.
// dh==0 blocks additionally emit xf (bf16 fragment layout) and rowsums.
__global__ __launch_bounds__(512, 4) void k_gram(
        const float* __restrict__ x, float* __restrict__ part,
        float* __restrict__ rspart, short* __restrict__ xf, int wxf) {
    __shared__ short Xs[2 * 256 * 72];   // 2 buffers, 256 rows x 144B pitch
    __shared__ float rs_s[256];
    const int t = threadIdx.x, lane = t & 63, wave = t >> 6;
    const int chunk = blockIdx.x, dh = blockIdx.y, b = blockIdx.z;
    const int k0 = chunk * (T_ * 64);
    const int f4 = t & 15;               // 16B col chunk (16 -> 64 cols)
    const int crow = t >> 4;             // 0..31 ; rows p*32 + crow
    const int cw0 = (wave & 3) * 64;
    const int dw0 = dh * 128 + (wave >> 2) * 64;
    const int r16 = lane & 15, g16 = lane >> 4;
    const float* xb = x + (size_t)b * CN_;
    short* xfb = xf + (size_t)b * CN_;
    const bool doaux = (dh == 0);

    f32x4 acc[4][4];
#pragma unroll
    for (int i = 0; i < 4; ++i)
#pragma unroll
        for (int j = 0; j < 4; ++j) acc[i][j] = f32x4{0.f, 0.f, 0.f, 0.f};
    float rs[8] = {0.f, 0.f, 0.f, 0.f, 0.f, 0.f, 0.f, 0.f};

    for (int tt = 0; tt < T_; ++tt) {
        const int buf = (tt & 1) * 18432;          // shorts
        // direct load -> convert -> LDS (latency hidden by the co-resident block)
        f32x4 v[8];
#pragma unroll
        for (int p = 0; p < 8; ++p)
            v[p] = *(const f32x4*)(xb + (size_t)(p * 32 + crow) * N_ +
                                   k0 + tt * 64 + f4 * 4);
#pragma unroll
        for (int p = 0; p < 8; ++p) {
            if (doaux) rs[p] += (v[p].x + v[p].y) + (v[p].z + v[p].w);
            bf16x4 h;
            h.x = f2bf(v[p].x); h.y = f2bf(v[p].y);
            h.z = f2bf(v[p].z); h.w = f2bf(v[p].w);
            *(bf16x4*)(Xs + buf + (p * 32 + crow) * 72 + f4 * 4) = h;
        }
        __syncthreads();
        // emit xf (bf16 fragment layout) from the staged tile (dh0 only)
        if (doaux && wxf) {
            const int ng0 = k0 + tt * 64;
#pragma unroll
            for (int it = 0; it < 4; ++it) {
                int s = it * 512 + t;
                int kg = s >> 6, nn = s & 63;
                bf16x8 h;
#pragma unroll
                for (int j = 0; j < 8; ++j)
                    h[j] = Xs[buf + (kg * 8 + j) * 72 + nn];
                *(bf16x8*)(xfb + ((size_t)kg * N_ + ng0 + nn) * 8) = h;
            }
        }
        // MFMA over K=64 (2 k-steps of 32)
#pragma unroll
        for (int kst = 0; kst < 2; ++kst) {
            bf16x8 afr[4];
#pragma unroll
            for (int ct = 0; ct < 4; ++ct)
                afr[ct] = *(const bf16x8*)(Xs + buf + (cw0 + ct * 16 + r16) * 72 +
                                           kst * 32 + g16 * 8);
#pragma unroll
            for (int dt = 0; dt < 4; ++dt) {
                bf16x8 bfr = *(const bf16x8*)(Xs + buf + (dw0 + dt * 16 + r16) * 72 +
                                              kst * 32 + g16 * 8);
#pragma unroll
                for (int ct = 0; ct < 4; ++ct)
                    acc[ct][dt] = __builtin_amdgcn_mfma_f32_16x16x32_bf16(
                        afr[ct], bfr, acc[ct][dt], 0, 0, 0);
            }
        }
    }

    if (doaux) {
        // rowsums: 16 threads (f4) share each row
#pragma unroll
        for (int p = 0; p < 8; ++p) {
            float r = rs[p];
            r += __shfl_xor(r, 1);
            r += __shfl_xor(r, 2);
            r += __shfl_xor(r, 4);
            r += __shfl_xor(r, 8);
            if ((t & 15) == 0) rs_s[p * 32 + crow] = r;
        }
        __syncthreads();
        if (t < 256) rspart[((size_t)b * NCK_ + chunk) * C_ + t] = rs_s[t];
    }

    float* pp = part + ((size_t)b * NCK_ + chunk) * (C_ * C_);
#pragma unroll
    for (int ct = 0; ct < 4; ++ct)
#pragma unroll
        for (int dt = 0; dt < 4; ++dt) {
            int d = dw0 + dt * 16 + r16;
#pragma unroll
            for (int rr = 0; rr < 4; ++rr) {
                int c = cw0 + ct * 16 + g16 * 4 + rr;
                pp[(size_t)c * C_ + d] = acc[ct][dt][rr];
            }
        }
}

// ------------- reduce partial Grams + fused stats (mean, rsig) -----------
__global__ void k_reduce(const float* __restrict__ part, const float* __restrict__ rspart,
                         float* __restrict__ Graw, float* __restrict__ mean,
                         float* __restrict__ rsig) {
    __shared__ float diag_s;
    __shared__ float red[256];
    int bid = blockIdx.x;
    int b = bid >> 8, c = bid & 255;
    int d = threadIdx.x;
    float s = 0.f;
    for (int p = 0; p < NCK_; ++p)
        s += part[(((size_t)b * NCK_ + p) * (C_ * C_)) + (size_t)c * C_ + d];
    Graw[((size_t)b * C_ + c) * C_ + d] = s;
    if (d == c) diag_s = s;
    float rsum = 0.f;
    for (int p = d; p < NCK_; p += 256)
        rsum += rspart[((size_t)b * NCK_ + p) * C_ + c];
    red[d] = rsum;
    __syncthreads();
    if (d < 128) red[d] += red[d + 128];
    __syncthreads();
    if (d < 64) red[d] += red[d + 64];
    __syncthreads();
    if (d == 0) {
        float tot = 0.f;
#pragma unroll
        for (int i = 0; i < 64; ++i) tot += red[i];
        float m = tot / (float)N_;
        float var = diag_s / (float)N_ - m * m;
        mean[b * C_ + c] = m;
        rsig[b * C_ + c] = rsqrtf(var + 1e-5f);
    }
}

// ---------------- P = Wq * Gn ----------------
__global__ void k_gemm1(const float* __restrict__ Wq, const float* __restrict__ Graw,
                        const float* __restrict__ mean, const float* __restrict__ rsig,
                        float* __restrict__ P) {
    int bid = blockIdx.x; int b = bid >> 8, c = bid & 255; int d = threadIdx.x;
    const float* G = Graw + (size_t)b * C_ * C_;
    const float* mb = mean + b * C_;
    const float* rb = rsig + b * C_;
    float md = mb[d], rd = rb[d];
    float a1 = 0.f, a2 = 0.f;
    for (int e = 0; e < C_; ++e) {
        float w = Wq[(size_t)c * C_ + e] * rb[e];
        a1 += w * G[(size_t)e * C_ + d];
        a2 += w * mb[e];
    }
    P[((size_t)b * C_ + c) * C_ + d] = rd * a1 - (float)N_ * md * rd * a2;
}

// ---------------- atten = softmax(P*Wk^T + N bq bk^T)/16 + outer/16 ------
__global__ void k_attn(const float* __restrict__ P, const float* __restrict__ Wk,
                       const float* __restrict__ bq, const float* __restrict__ bk,
                       const float* __restrict__ outer, float* __restrict__ atten) {
    __shared__ float Pr_s[256];
    __shared__ float red[8];
    int bid = blockIdx.x; int b = bid >> 8, c = bid & 255; int d = threadIdx.x;
    int lane = d & 63, w = d >> 6;
    Pr_s[d] = P[((size_t)b * C_ + c) * C_ + d];
    __syncthreads();
    float a = 0.f;
#pragma unroll 4
    for (int e4 = 0; e4 < 64; ++e4) {
        f32x4 wv = *(const f32x4*)(Wk + (size_t)d * C_ + e4 * 4);
        f32x4 pv = *(const f32x4*)(Pr_s + e4 * 4);
        a += wv.x * pv.x + wv.y * pv.y + wv.z * pv.z + wv.w * pv.w;
    }
    float v = a + (float)N_ * bq[c] * bk[d];
    float m = v;
    for (int off = 32; off; off >>= 1) m = fmaxf(m, __shfl_xor(m, off));
    if (lane == 0) red[w] = m;
    __syncthreads();
    m = fmaxf(fmaxf(red[0], red[1]), fmaxf(red[2], red[3]));
    float e = __expf(v - m);
    float s = e;
    for (int off = 32; off; off >>= 1) s += __shfl_xor(s, off);
    if (lane == 0) red[4 + w] = s;
    __syncthreads();
    s = red[4] + red[5] + red[6] + red[7];
    atten[((size_t)b * C_ + c) * C_ + d] = e / (s * 16.f) + outer[(size_t)c * C_ + d] * 0.0625f;
}

// ------------- A = (atten*Wv + I)*diag(rsig) in FRAGMENT layout, beta ----
__global__ void k_gemm3(const float* __restrict__ atten, const float* __restrict__ Wv,
                        const float* __restrict__ bv, const float* __restrict__ mean,
                        const float* __restrict__ rsig, short* __restrict__ Abf,
                        float* __restrict__ beta) {
    __shared__ float red[4];
    int bid = blockIdx.x; int b = bid >> 8, c = bid & 255; int g = threadIdx.x;
    int lane = g & 63, w = g >> 6;
    const float* at = atten + ((size_t)b * C_ + c) * C_;
    float a = 0.f;
    for (int d = 0; d < C_; ++d)
        a += at[d] * Wv[(size_t)d * C_ + g];
    float Ag = (a + ((g == c) ? 1.f : 0.f)) * rsig[b * C_ + g];
    Abf[(size_t)b * C_ * C_ + ((size_t)(g >> 3) * C_ + c) * 8 + (g & 7)] = f2bf(Ag);
    float u = at[g] * bv[g] - Ag * mean[b * C_ + g];
    for (int off = 32; off; off >>= 1) u += __shfl_xor(u, off);
    if (lane == 0) red[w] = u;
    __syncthreads();
    if (g == 0) beta[b * C_ + c] = red[0] + red[1] + red[2] + red[3];
}

// ------------- Pass 2: out = A*x + beta ------------------------------------
__global__ __launch_bounds__(512, 4) void k_out2(
        const short* __restrict__ xf, const short* __restrict__ Abf,
        const float* __restrict__ beta, float* __restrict__ out) {
    __shared__ short Xt[2 * 8192];      // 2 x 16 KB
    __shared__ float Wb[8 * 32 * 33];   // wave-private store-transpose
    const int t = threadIdx.x, lane = t & 63, wave = t >> 6;
    const int nb = blockIdx.x, b = blockIdx.y;
    const int col = lane & 15, g16 = lane >> 4;
    const int cw0 = wave * 32;
    const int r8 = lane >> 3, s8 = lane & 7;
    const int n_blk = nb * 256;
    const short* Ab = Abf + (size_t)b * C_ * C_;
    const short* xfb = xf + (size_t)b * CN_;
    float* ob = out + (size_t)b * CN_;
    float* wl = Wb + wave * (32 * 33);

    // A-slice preload: 16 frags = 64 VGPR
    bf16x8 Af[2][8];
#pragma unroll
    for (int ct = 0; ct < 2; ++ct)
#pragma unroll
        for (int ks = 0; ks < 8; ++ks)
            Af[ct][ks] = *(const bf16x8*)(Ab +
                ((size_t)((ks * 4 + g16) * 256 + cw0 + ct * 16 + col)) * 8);
    float bet[4];
#pragma unroll
    for (int j = 0; j < 4; ++j) bet[j] = beta[b * C_ + cw0 + j * 8 + r8];

#define STAGE(BUF, N0)                                                        \
    {                                                                         \
        _Pragma("unroll")                                                     \
        for (int r = 0; r < 2; ++r) {                                         \
            int s = r * 512 + t;                                              \
            int kg = s >> 5, nsl = s & 31;                                    \
            int nn = nsl ^ (kg & 3);                                          \
            gload16(xfb + ((size_t)kg * N_ + (N0) + nn) * 8,                  \
                    Xt + (BUF) * 8192 + s * 8);                               \
        }                                                                     \
    }

    STAGE(0, n_blk)
    __syncthreads();

    for (int it = 0; it < 8; ++it) {
        const int cur = it & 1;
        if (it + 1 < 8) STAGE(cur ^ 1, n_blk + (it + 1) * 32)
        const int n0 = n_blk + it * 32;

        f32x4 acc[2][2];
#pragma unroll
        for (int i = 0; i < 2; ++i) {
            acc[i][0] = f32x4{0.f, 0.f, 0.f, 0.f};
            acc[i][1] = f32x4{0.f, 0.f, 0.f, 0.f};
        }
#pragma unroll
        for (int ks = 0; ks < 8; ++ks) {
            const int kg = ks * 4 + g16;
            bf16x8 x0 = *(const bf16x8*)(Xt + cur * 8192 +
                                         (kg * 32 + (col ^ (kg & 3))) * 8);
            bf16x8 x1 = *(const bf16x8*)(Xt + cur * 8192 +
                                         (kg * 32 + ((16 + col) ^ (kg & 3))) * 8);
            acc[0][0] = __builtin_amdgcn_mfma_f32_16x16x32_bf16(Af[0][ks], x0, acc[0][0], 0, 0, 0);
            acc[1][0] = __builtin_amdgcn_mfma_f32_16x16x32_bf16(Af[1][ks], x0, acc[1][0], 0, 0, 0);
            acc[0][1] = __builtin_amdgcn_mfma_f32_16x16x32_bf16(Af[0][ks], x1, acc[0][1], 0, 0, 0);
            acc[1][1] = __builtin_amdgcn_mfma_f32_16x16x32_bf16(Af[1][ks], x1, acc[1][1], 0, 0, 0);
        }
        // wave-private transpose (pitch 33 -> ~2-way banks)
#pragma unroll
        for (int ct = 0; ct < 2; ++ct)
#pragma unroll
            for (int nt = 0; nt < 2; ++nt)
#pragma unroll
                for (int rr = 0; rr < 4; ++rr)
                    wl[(ct * 16 + g16 * 4 + rr) * 33 + nt * 16 + col] = acc[ct][nt][rr];
#pragma unroll
        for (int j = 0; j < 4; ++j) {
            f32x4 v = *(const f32x4*)(wl + (j * 8 + r8) * 33 + s8 * 4);
            float bb = bet[j];
            v.x += bb; v.y += bb; v.z += bb; v.w += bb;
            *(f32x4*)(ob + (size_t)(cw0 + j * 8 + r8) * N_ + n0 + s8 * 4) = v;
        }
        __syncthreads();
    }
#undef STAGE
}

// ------------- Pass 2 (fallback, small ws): gathers f32 x ----------------
__global__ __launch_bounds__(512) void k_out_f32(
        const float* __restrict__ x, const short* __restrict__ Abf,
        const float* __restrict__ beta, float* __restrict__ out) {
    __shared__ float beta_s[256];
    const int t = threadIdx.x, lane = t & 63, wave = t >> 6;
    const int nb = blockIdx.x, b = blockIdx.y;
    const int col = lane & 15, g16 = lane >> 4;
    const int n_w = nb * 256 + wave * 32;
    if (t < 256) beta_s[t] = beta[b * C_ + t];
    __syncthreads();
    const short* Ab = Abf + (size_t)b * C_ * C_;
    const float* xb = x + (size_t)b * CN_;
    float* ob = out + (size_t)b * CN_;

    f32x4 acc[16][2];
#pragma unroll
    for (int i = 0; i < 16; ++i) {
        acc[i][0] = f32x4{0.f, 0.f, 0.f, 0.f};
        acc[i][1] = f32x4{0.f, 0.f, 0.f, 0.f};
    }
    float pf[2][16];
#define XL(KS, NT, J) xb[(size_t)((KS)*32 + g16 * 8 + (J)) * N_ + n_w + (NT)*16 + col]
#pragma unroll
    for (int j = 0; j < 8; ++j) { pf[0][j] = XL(0, 0, j); pf[0][8 + j] = XL(0, 1, j); }
#pragma unroll
    for (int ks = 0; ks < 8; ++ks) {
        if (ks + 1 < 8) {
#pragma unroll
            for (int j = 0; j < 8; ++j) {
                pf[(ks + 1) & 1][j] = XL(ks + 1, 0, j);
                pf[(ks + 1) & 1][8 + j] = XL(ks + 1, 1, j);
            }
        }
        bf16x8 xa, xv;
#pragma unroll
        for (int j = 0; j < 8; ++j) {
            xa[j] = f2bf(pf[ks & 1][j]);
            xv[j] = f2bf(pf[ks & 1][8 + j]);
        }
#pragma unroll
        for (int ct = 0; ct < 16; ++ct) {
            bf16x8 afr = *(const bf16x8*)(Ab + ((size_t)((ks * 4 + g16) * 256 + ct * 16 + col)) * 8);
            acc[ct][0] = __builtin_amdgcn_mfma_f32_16x16x32_bf16(afr, xa, acc[ct][0], 0, 0, 0);
            acc[ct][1] = __builtin_amdgcn_mfma_f32_16x16x32_bf16(afr, xv, acc[ct][1], 0, 0, 0);
        }
    }
#undef XL
#pragma unroll
    for (int ct = 0; ct < 16; ++ct)
#pragma unroll
        for (int nt = 0; nt < 2; ++nt) {
            int n = n_w + nt * 16 + col;
#pragma unroll
            for (int rr = 0; rr < 4; ++rr) {
                int c = ct * 16 + g16 * 4 + rr;
                ob[(size_t)c * N_ + n] = acc[ct][nt][rr] + beta_s[c];
            }
        }
}

extern "C" void kernel_launch(void* const* d_in, const int* in_sizes, int n_in,
                              void* d_out, int out_size, void* d_ws, size_t ws_size,
                              hipStream_t stream) {
    (void)in_sizes; (void)n_in; (void)out_size;
    const float* x     = (const float*)d_in[0];
    const float* Wq    = (const float*)d_in[1];
    const float* bq    = (const float*)d_in[2];
    const float* Wk    = (const float*)d_in[3];
    const float* bk    = (const float*)d_in[4];
    const float* Wv    = (const float*)d_in[5];
    const float* bv    = (const float*)d_in[6];
    const float* outer = (const float*)d_in[7];
    float* out = (float*)d_out;

    char* w = (char*)d_ws;
    float* mean   = (float*)(w + 0);
    float* rsig   = (float*)(w + 2048);
    float* beta   = (float*)(w + 4096);
    float* rspart = (float*)(w + 8192);                 // 108*2*256*4 = 221184
    float* Graw   = (float*)(w + 262144);               // 512K
    float* P      = (float*)(w + 786432);               // 512K
    float* atten  = (float*)(w + 1310720);              // 512K
    short* Abf    = (short*)(w + 1835008);              // 256K
    const size_t fixed = 2097152;                       // 2 MB
    const size_t part_bytes = (size_t)NCK_ * B_ * C_ * C_ * 4;   // 56.6 MB
    const size_t xf_bytes = (size_t)B_ * CN_ * 2;                // 113.25 MB
    float* part = (float*)(w + fixed);
    short* xf   = (short*)(w + fixed + part_bytes);

    const bool big = ws_size >= fixed + part_bytes + xf_bytes;

    k_gram  <<<dim3(NCK_, 2, B_), 512, 0, stream>>>(x, part, rspart, xf, big ? 1 : 0);
    k_reduce<<<dim3(B_ * C_), 256, 0, stream>>>(part, rspart, Graw, mean, rsig);
    k_gemm1 <<<dim3(B_ * C_), C_, 0, stream>>>(Wq, Graw, mean, rsig, P);
    k_attn  <<<dim3(B_ * C_), C_, 0, stream>>>(P, Wk, bq, bk, outer, atten);
    k_gemm3 <<<dim3(B_ * C_), C_, 0, stream>>>(atten, Wv, bv, mean, rsig, Abf, beta);
    if (big) {
        k_out2  <<<dim3(N_ / 256, B_), 512, 0, stream>>>(xf, Abf, beta, out);
    } else {
        k_out_f32<<<dim3(N_ / 256, B_), 512, 0, stream>>>(x, Abf, beta, out);
    }
}

// Round 10
// 228.992 us; speedup vs baseline: 3.1448x; 1.2451x over previous
//
#include <hip/hip_runtime.h>
#include <hip/hip_bf16.h>

#define B_ 2
#define C_ 256
#define N_ 110592
#define CN_ ((size_t)C_ * N_)
#define NCK_ 128          // K-chunks in gram (exactly 256 blocks)
#define TW_ 32            // tile width in f32 cols
#define T_ 27             // tiles per chunk: 128*27*32 = 110592

typedef __attribute__((ext_vector_type(4))) float f32x4;
typedef __attribute__((ext_vector_type(8))) short bf16x8;
typedef __attribute__((ext_vector_type(4))) short bf16x4;

__device__ __forceinline__ short f2bf(float f) {
    union { float f; unsigned u; } v; v.f = f;
    unsigned r = (v.u + 0x7fffu + ((v.u >> 16) & 1u)) >> 16;
    return (short)(r & 0xffffu);
}

__device__ __forceinline__ void gload16f(const float* g, float* l) {
    __builtin_amdgcn_global_load_lds(
        (const __attribute__((address_space(1))) void*)g,
        (__attribute__((address_space(3))) void*)l, 16, 0, 0);
}

__device__ __forceinline__ void gload16s(const short* g, short* l) {
    __builtin_amdgcn_global_load_lds(
        (const __attribute__((address_space(1))) void*)g,
        (__attribute__((address_space(3))) void*)l, 16, 0, 0);
}

// ---------------- Pass 1: raw Gram + rowsums + xf emit --------------------
// 1024 thr / 16 waves, 1 block/CU (grid 256). 3-deep global_load_lds
// pipeline with counted vmcnt + raw barriers. vmcnt(2) is robust to the
// early-retiring emit stores in the FIFO: loads retire in-order among
// loads, so <=2 outstanding forces the needed tile's 2 loads to be done.
__global__ __launch_bounds__(1024, 4) void k_gram(
        const float* __restrict__ x, float* __restrict__ part,
        float* __restrict__ rspart, short* __restrict__ xf, int wxf) {
    __shared__ float Xf[3 * 8192];      // 3 x 32 KB f32 tile buffers
    __shared__ short Xb[256 * 40];      // 20 KB bf16 tile, pitch 40 shorts
    __shared__ float rs_s[256];
    const int t = threadIdx.x, lane = t & 63, wave = t >> 6;
    const int chunk = blockIdx.x, b = blockIdx.y;
    const int k0 = chunk * (T_ * TW_);
    const int cw0 = (wave & 3) * 64, dw0 = (wave >> 2) * 64;
    const int r16 = lane & 15, g16 = lane >> 4;
    const float* xb = x + (size_t)b * CN_;
    short* xfb = xf + (size_t)b * CN_;

    // stage geometry: slot s -> row s>>3, slot-group s&7 holds source group
    // (s&7)^(row&7). Thread t covers slots t and t+1024 (rows r, r+128).
    const int s_row = t >> 3;
    const int g_src = (t & 7) ^ (s_row & 7);
    // repack geometry: row t>>2, col-quarter t&3
    const int rp_r = t >> 2, rp_q = t & 3;
    const int rp_g0 = (2 * rp_q) ^ (rp_r & 7);
    // emit geometry
    const int em_cg = t >> 5, em_nn = t & 31;

    f32x4 acc[4][4];
#pragma unroll
    for (int i = 0; i < 4; ++i)
#pragma unroll
        for (int j = 0; j < 4; ++j) acc[i][j] = f32x4{0.f, 0.f, 0.f, 0.f};
    float rs = 0.f;

#define GSTAGE(TT, BB)                                                        \
    {                                                                         \
        const float* gsrc = xb + k0 + (TT) * TW_ + g_src * 4;                 \
        float* ldst = Xf + (BB) * 8192;                                       \
        gload16f(gsrc + (size_t)s_row * N_, ldst + t * 4);                    \
        gload16f(gsrc + (size_t)(s_row + 128) * N_, ldst + (t + 1024) * 4);   \
    }

    GSTAGE(0, 0)
    GSTAGE(1, 1)

    int bb = 0;
    for (int tt = 0; tt < T_; ++tt) {
        asm volatile("s_waitcnt vmcnt(2)" ::: "memory");
        __builtin_amdgcn_s_barrier();
        if (tt + 2 < T_) {
            int bn = bb + 2; if (bn >= 3) bn -= 3;
            GSTAGE(tt + 2, bn)
        }
        // repack f32 -> bf16 (+ rowsum, exact f32)
        {
            const float* src = Xf + bb * 8192 + rp_r * 32;
            f32x4 a = *(const f32x4*)(src + rp_g0 * 4);
            f32x4 c = *(const f32x4*)(src + (rp_g0 ^ 1) * 4);
            rs += ((a.x + a.y) + (a.z + a.w)) + ((c.x + c.y) + (c.z + c.w));
            bf16x8 h;
            h[0] = f2bf(a.x); h[1] = f2bf(a.y); h[2] = f2bf(a.z); h[3] = f2bf(a.w);
            h[4] = f2bf(c.x); h[5] = f2bf(c.y); h[6] = f2bf(c.z); h[7] = f2bf(c.w);
            *(bf16x8*)(Xb + rp_r * 40 + rp_q * 8) = h;
        }
        asm volatile("s_waitcnt lgkmcnt(0)" ::: "memory");
        __builtin_amdgcn_s_barrier();
        // MFMA (K=32, one step per tile)
        {
            bf16x8 afr[4];
#pragma unroll
            for (int ct = 0; ct < 4; ++ct)
                afr[ct] = *(const bf16x8*)(Xb + (cw0 + ct * 16 + r16) * 40 + g16 * 8);
#pragma unroll
            for (int dt = 0; dt < 4; ++dt) {
                bf16x8 bfr = *(const bf16x8*)(Xb + (dw0 + dt * 16 + r16) * 40 + g16 * 8);
#pragma unroll
                for (int ct = 0; ct < 4; ++ct)
                    acc[ct][dt] = __builtin_amdgcn_mfma_f32_16x16x32_bf16(
                        afr[ct], bfr, acc[ct][dt], 0, 0, 0);
            }
        }
        // emit xf (bf16 fragment layout [cg][n][8])
        if (wxf) {
            bf16x8 h;
#pragma unroll
            for (int j = 0; j < 8; ++j)
                h[j] = Xb[(em_cg * 8 + j) * 40 + em_nn];
            *(bf16x8*)(xfb + ((size_t)em_cg * N_ + k0 + tt * TW_ + em_nn) * 8) = h;
        }
        ++bb; if (bb >= 3) bb -= 3;
    }
#undef GSTAGE

    // rowsums: 4 threads share each row
    rs += __shfl_xor(rs, 1);
    rs += __shfl_xor(rs, 2);
    if (rp_q == 0) rs_s[rp_r] = rs;
    __syncthreads();
    if (t < 256) rspart[((size_t)b * NCK_ + chunk) * C_ + t] = rs_s[t];

    float* pp = part + ((size_t)b * NCK_ + chunk) * (C_ * C_);
#pragma unroll
    for (int ct = 0; ct < 4; ++ct)
#pragma unroll
        for (int dt = 0; dt < 4; ++dt) {
            int d = dw0 + dt * 16 + r16;
#pragma unroll
            for (int rr = 0; rr < 4; ++rr) {
                int c = cw0 + ct * 16 + g16 * 4 + rr;
                pp[(size_t)c * C_ + d] = acc[ct][dt][rr];
            }
        }
}

// ------------- reduce partial Grams + fused stats (mean, rsig) -----------
__global__ void k_reduce(const float* __restrict__ part, const float* __restrict__ rspart,
                         float* __restrict__ Graw, float* __restrict__ mean,
                         float* __restrict__ rsig) {
    __shared__ float diag_s;
    __shared__ float red[256];
    int bid = blockIdx.x;
    int b = bid >> 8, c = bid & 255;
    int d = threadIdx.x;
    float s = 0.f;
    for (int p = 0; p < NCK_; ++p)
        s += part[(((size_t)b * NCK_ + p) * (C_ * C_)) + (size_t)c * C_ + d];
    Graw[((size_t)b * C_ + c) * C_ + d] = s;
    if (d == c) diag_s = s;
    float rsum = 0.f;
    for (int p = d; p < NCK_; p += 256)
        rsum += rspart[((size_t)b * NCK_ + p) * C_ + c];
    red[d] = rsum;
    __syncthreads();
    if (d < 128) red[d] += red[d + 128];
    __syncthreads();
    if (d < 64) red[d] += red[d + 64];
    __syncthreads();
    if (d == 0) {
        float tot = 0.f;
#pragma unroll
        for (int i = 0; i < 64; ++i) tot += red[i];
        float m = tot / (float)N_;
        float var = diag_s / (float)N_ - m * m;
        mean[b * C_ + c] = m;
        rsig[b * C_ + c] = rsqrtf(var + 1e-5f);
    }
}

// ---------------- P = Wq * Gn ----------------
__global__ void k_gemm1(const float* __restrict__ Wq, const float* __restrict__ Graw,
                        const float* __restrict__ mean, const float* __restrict__ rsig,
                        float* __restrict__ P) {
    int bid = blockIdx.x; int b = bid >> 8, c = bid & 255; int d = threadIdx.x;
    const float* G = Graw + (size_t)b * C_ * C_;
    const float* mb = mean + b * C_;
    const float* rb = rsig + b * C_;
    float md = mb[d], rd = rb[d];
    float a1 = 0.f, a2 = 0.f;
    for (int e = 0; e < C_; ++e) {
        float w = Wq[(size_t)c * C_ + e] * rb[e];
        a1 += w * G[(size_t)e * C_ + d];
        a2 += w * mb[e];
    }
    P[((size_t)b * C_ + c) * C_ + d] = rd * a1 - (float)N_ * md * rd * a2;
}

// ---------------- atten = softmax(P*Wk^T + N bq bk^T)/16 + outer/16 ------
__global__ void k_attn(const float* __restrict__ P, const float* __restrict__ Wk,
                       const float* __restrict__ bq, const float* __restrict__ bk,
                       const float* __restrict__ outer, float* __restrict__ atten) {
    __shared__ float Pr_s[256];
    __shared__ float red[8];
    int bid = blockIdx.x; int b = bid >> 8, c = bid & 255; int d = threadIdx.x;
    int lane = d & 63, w = d >> 6;
    Pr_s[d] = P[((size_t)b * C_ + c) * C_ + d];
    __syncthreads();
    float a = 0.f;
#pragma unroll 4
    for (int e4 = 0; e4 < 64; ++e4) {
        f32x4 wv = *(const f32x4*)(Wk + (size_t)d * C_ + e4 * 4);
        f32x4 pv = *(const f32x4*)(Pr_s + e4 * 4);
        a += wv.x * pv.x + wv.y * pv.y + wv.z * pv.z + wv.w * pv.w;
    }
    float v = a + (float)N_ * bq[c] * bk[d];
    float m = v;
    for (int off = 32; off; off >>= 1) m = fmaxf(m, __shfl_xor(m, off));
    if (lane == 0) red[w] = m;
    __syncthreads();
    m = fmaxf(fmaxf(red[0], red[1]), fmaxf(red[2], red[3]));
    float e = __expf(v - m);
    float s = e;
    for (int off = 32; off; off >>= 1) s += __shfl_xor(s, off);
    if (lane == 0) red[4 + w] = s;
    __syncthreads();
    s = red[4] + red[5] + red[6] + red[7];
    atten[((size_t)b * C_ + c) * C_ + d] = e / (s * 16.f) + outer[(size_t)c * C_ + d] * 0.0625f;
}

// ------------- A = (atten*Wv + I)*diag(rsig) in FRAGMENT layout, beta ----
__global__ void k_gemm3(const float* __restrict__ atten, const float* __restrict__ Wv,
                        const float* __restrict__ bv, const float* __restrict__ mean,
                        const float* __restrict__ rsig, short* __restrict__ Abf,
                        float* __restrict__ beta) {
    __shared__ float red[4];
    int bid = blockIdx.x; int b = bid >> 8, c = bid & 255; int g = threadIdx.x;
    int lane = g & 63, w = g >> 6;
    const float* at = atten + ((size_t)b * C_ + c) * C_;
    float a = 0.f;
    for (int d = 0; d < C_; ++d)
        a += at[d] * Wv[(size_t)d * C_ + g];
    float Ag = (a + ((g == c) ? 1.f : 0.f)) * rsig[b * C_ + g];
    Abf[(size_t)b * C_ * C_ + ((size_t)(g >> 3) * C_ + c) * 8 + (g & 7)] = f2bf(Ag);
    float u = at[g] * bv[g] - Ag * mean[b * C_ + g];
    for (int off = 32; off; off >>= 1) u += __shfl_xor(u, off);
    if (lane == 0) red[w] = u;
    __syncthreads();
    if (g == 0) beta[b * C_ + c] = red[0] + red[1] + red[2] + red[3];
}

// ------------- Pass 2: out = A*x + beta (R8 known-good version) -----------
// NOTE: counted-vmcnt was WRONG here (stores retire early; vmcnt(4) could
// pass with STAGE loads in flight). __syncthreads() per iteration is safe.
__global__ __launch_bounds__(512, 4) void k_out2(
        const short* __restrict__ xf, const short* __restrict__ Abf,
        const float* __restrict__ beta, float* __restrict__ out) {
    __shared__ short Xt[2 * 8192];      // 2 x 16 KB
    __shared__ float Wb[8 * 32 * 33];   // wave-private store-transpose
    const int t = threadIdx.x, lane = t & 63, wave = t >> 6;
    const int nb = blockIdx.x, b = blockIdx.y;
    const int col = lane & 15, g16 = lane >> 4;
    const int cw0 = wave * 32;
    const int r8 = lane >> 3, s8 = lane & 7;
    const int n_blk = nb * 256;
    const short* Ab = Abf + (size_t)b * C_ * C_;
    const short* xfb = xf + (size_t)b * CN_;
    float* ob = out + (size_t)b * CN_;
    float* wl = Wb + wave * (32 * 33);

    // A-slice preload: 16 frags = 64 VGPR
    bf16x8 Af[2][8];
#pragma unroll
    for (int ct = 0; ct < 2; ++ct)
#pragma unroll
        for (int ks = 0; ks < 8; ++ks)
            Af[ct][ks] = *(const bf16x8*)(Ab +
                ((size_t)((ks * 4 + g16) * 256 + cw0 + ct * 16 + col)) * 8);
    float bet[4];
#pragma unroll
    for (int j = 0; j < 4; ++j) bet[j] = beta[b * C_ + cw0 + j * 8 + r8];

#define STAGE(BUF, N0)                                                        \
    {                                                                         \
        _Pragma("unroll")                                                     \
        for (int r = 0; r < 2; ++r) {                                         \
            int s = r * 512 + t;                                              \
            int kg = s >> 5, nsl = s & 31;                                    \
            int nn = nsl ^ (kg & 3);                                          \
            gload16s(xfb + ((size_t)kg * N_ + (N0) + nn) * 8,                 \
                     Xt + (BUF) * 8192 + s * 8);                              \
        }                                                                     \
    }

    STAGE(0, n_blk)
    __syncthreads();

    for (int it = 0; it < 8; ++it) {
        const int cur = it & 1;
        if (it + 1 < 8) STAGE(cur ^ 1, n_blk + (it + 1) * 32)
        const int n0 = n_blk + it * 32;

        f32x4 acc[2][2];
#pragma unroll
        for (int i = 0; i < 2; ++i) {
            acc[i][0] = f32x4{0.f, 0.f, 0.f, 0.f};
            acc[i][1] = f32x4{0.f, 0.f, 0.f, 0.f};
        }
#pragma unroll
        for (int ks = 0; ks < 8; ++ks) {
            const int kg = ks * 4 + g16;
            bf16x8 x0 = *(const bf16x8*)(Xt + cur * 8192 +
                                         (kg * 32 + (col ^ (kg & 3))) * 8);
            bf16x8 x1 = *(const bf16x8*)(Xt + cur * 8192 +
                                         (kg * 32 + ((16 + col) ^ (kg & 3))) * 8);
            acc[0][0] = __builtin_amdgcn_mfma_f32_16x16x32_bf16(Af[0][ks], x0, acc[0][0], 0, 0, 0);
            acc[1][0] = __builtin_amdgcn_mfma_f32_16x16x32_bf16(Af[1][ks], x0, acc[1][0], 0, 0, 0);
            acc[0][1] = __builtin_amdgcn_mfma_f32_16x16x32_bf16(Af[0][ks], x1, acc[0][1], 0, 0, 0);
            acc[1][1] = __builtin_amdgcn_mfma_f32_16x16x32_bf16(Af[1][ks], x1, acc[1][1], 0, 0, 0);
        }
        // wave-private transpose (pitch 33 -> ~2-way banks)
#pragma unroll
        for (int ct = 0; ct < 2; ++ct)
#pragma unroll
            for (int nt = 0; nt < 2; ++nt)
#pragma unroll
                for (int rr = 0; rr < 4; ++rr)
                    wl[(ct * 16 + g16 * 4 + rr) * 33 + nt * 16 + col] = acc[ct][nt][rr];
#pragma unroll
        for (int j = 0; j < 4; ++j) {
            f32x4 v = *(const f32x4*)(wl + (j * 8 + r8) * 33 + s8 * 4);
            float bb = bet[j];
            v.x += bb; v.y += bb; v.z += bb; v.w += bb;
            *(f32x4*)(ob + (size_t)(cw0 + j * 8 + r8) * N_ + n0 + s8 * 4) = v;
        }
        __syncthreads();
    }
#undef STAGE
}

// ------------- Pass 2 (fallback, small ws): gathers f32 x ----------------
__global__ __launch_bounds__(512) void k_out_f32(
        const float* __restrict__ x, const short* __restrict__ Abf,
        const float* __restrict__ beta, float* __restrict__ out) {
    __shared__ float beta_s[256];
    const int t = threadIdx.x, lane = t & 63, wave = t >> 6;
    const int nb = blockIdx.x, b = blockIdx.y;
    const int col = lane & 15, g16 = lane >> 4;
    const int n_w = nb * 256 + wave * 32;
    if (t < 256) beta_s[t] = beta[b * C_ + t];
    __syncthreads();
    const short* Ab = Abf + (size_t)b * C_ * C_;
    const float* xb = x + (size_t)b * CN_;
    float* ob = out + (size_t)b * CN_;

    f32x4 acc[16][2];
#pragma unroll
    for (int i = 0; i < 16; ++i) {
        acc[i][0] = f32x4{0.f, 0.f, 0.f, 0.f};
        acc[i][1] = f32x4{0.f, 0.f, 0.f, 0.f};
    }
    float pf[2][16];
#define XL(KS, NT, J) xb[(size_t)((KS)*32 + g16 * 8 + (J)) * N_ + n_w + (NT)*16 + col]
#pragma unroll
    for (int j = 0; j < 8; ++j) { pf[0][j] = XL(0, 0, j); pf[0][8 + j] = XL(0, 1, j); }
#pragma unroll
    for (int ks = 0; ks < 8; ++ks) {
        if (ks + 1 < 8) {
#pragma unroll
            for (int j = 0; j < 8; ++j) {
                pf[(ks + 1) & 1][j] = XL(ks + 1, 0, j);
                pf[(ks + 1) & 1][8 + j] = XL(ks + 1, 1, j);
            }
        }
        bf16x8 xa, xv;
#pragma unroll
        for (int j = 0; j < 8; ++j) {
            xa[j] = f2bf(pf[ks & 1][j]);
            xv[j] = f2bf(pf[ks & 1][8 + j]);
        }
#pragma unroll
        for (int ct = 0; ct < 16; ++ct) {
            bf16x8 afr = *(const bf16x8*)(Ab + ((size_t)((ks * 4 + g16) * 256 + ct * 16 + col)) * 8);
            acc[ct][0] = __builtin_amdgcn_mfma_f32_16x16x32_bf16(afr, xa, acc[ct][0], 0, 0, 0);
            acc[ct][1] = __builtin_amdgcn_mfma_f32_16x16x32_bf16(afr, xv, acc[ct][1], 0, 0, 0);
        }
    }
#undef XL
#pragma unroll
    for (int ct = 0; ct < 16; ++ct)
#pragma unroll
        for (int nt = 0; nt < 2; ++nt) {
            int n = n_w + nt * 16 + col;
#pragma unroll
            for (int rr = 0; rr < 4; ++rr) {
                int c = ct * 16 + g16 * 4 + rr;
                ob[(size_t)c * N_ + n] = acc[ct][nt][rr] + beta_s[c];
            }
        }
}

extern "C" void kernel_launch(void* const* d_in, const int* in_sizes, int n_in,
                              void* d_out, int out_size, void* d_ws, size_t ws_size,
                              hipStream_t stream) {
    (void)in_sizes; (void)n_in; (void)out_size;
    const float* x     = (const float*)d_in[0];
    const float* Wq    = (const float*)d_in[1];
    const float* bq    = (const float*)d_in[2];
    const float* Wk    = (const float*)d_in[3];
    const float* bk    = (const float*)d_in[4];
    const float* Wv    = (const float*)d_in[5];
    const float* bv    = (const float*)d_in[6];
    const float* outer = (const float*)d_in[7];
    float* out = (float*)d_out;

    char* w = (char*)d_ws;
    float* mean   = (float*)(w + 0);
    float* rsig   = (float*)(w + 2048);
    float* beta   = (float*)(w + 4096);
    float* rspart = (float*)(w + 8192);                 // 128*2*256*4 = 262144
    float* Graw   = (float*)(w + 270336);               // 512K
    float* P      = (float*)(w + 794624);               // 512K
    float* atten  = (float*)(w + 1318912);              // 512K
    short* Abf    = (short*)(w + 1843200);              // 256K -> 2105344
    const size_t fixed = 2105344;
    const size_t part_bytes = (size_t)NCK_ * B_ * C_ * C_ * 4;   // 67.1 MB
    const size_t xf_bytes = (size_t)B_ * CN_ * 2;                // 113.25 MB
    float* part = (float*)(w + fixed);
    short* xf   = (short*)(w + fixed + part_bytes);

    const bool big = ws_size >= fixed + part_bytes + xf_bytes;

    k_gram  <<<dim3(NCK_, B_), 1024, 0, stream>>>(x, part, rspart, xf, big ? 1 : 0);
    k_reduce<<<dim3(B_ * C_), 256, 0, stream>>>(part, rspart, Graw, mean, rsig);
    k_gemm1 <<<dim3(B_ * C_), C_, 0, stream>>>(Wq, Graw, mean, rsig, P);
    k_attn  <<<dim3(B_ * C_), C_, 0, stream>>>(P, Wk, bq, bk, outer, atten);
    k_gemm3 <<<dim3(B_ * C_), C_, 0, stream>>>(atten, Wv, bv, mean, rsig, Abf, beta);
    if (big) {
        k_out2  <<<dim3(N_ / 256, B_), 512, 0, stream>>>(xf, Abf, beta, out);
    } else {
        k_out_f32<<<dim3(N_ / 256, B_), 512, 0, stream>>>(x, Abf, beta, out);
    }
}